// Round 17
// baseline (439.652 us; speedup 1.0000x reference)
//
#include <hip/hip_runtime.h>

// AlignmentNet round 17: conv weights NOT staged in LDS at all — each lane
// loads its MFMA A-fragment directly from global (L1/L2-resident, identical
// across blocks). Conv-phase barriers 19 -> 3. Fused kernel LDS 36.3->31.7KB
// (5 blocks/CU); cr-conv LDS 61.9->41.5KB (3 blocks/CU). Deform phase
// unchanged (r16: 4x32 tile, packed-half2, sOff stride 168B).

using f16   = _Float16;
using f16x8 = __attribute__((ext_vector_type(8))) f16;
using h2    = __attribute__((ext_vector_type(2))) f16;
using u16x8 = __attribute__((ext_vector_type(8))) unsigned short;
using f32x4 = __attribute__((ext_vector_type(4))) float;

static constexpr int Hh = 128, Ww = 128, NB = 4, NPIX = Hh * Ww;
static constexpr int BB = 8;  // batch*branches

__device__ __forceinline__ unsigned short f2h(float f) {
  f16 h = (f16)f;
  return *(unsigned short*)&h;
}

// ---------------------------------------------------------------------------
// Fused weight prep. which: 0=cr, 1-4=off convs (cout padded 18->20 per g),
// 5-8=deform w, 9=off biases (padded to [80] in g*20+c layout).
// ---------------------------------------------------------------------------
struct PrepPtrs {
  const float* cw[5];
  unsigned short* cd[5];
  const float* dw[4];
  unsigned short* dd[4];
  const float* ob[4];
  float* obd[4];
};

__global__ __launch_bounds__(256) void prep_all_kernel(PrepPtrs pp) {
  const int which = blockIdx.y;
  const int i = blockIdx.x * 256 + threadIdx.x;
  if (which == 0) {
    if (i >= 9 * 64 * 128) return;
    const int cin = 128, cop = 64;
    const int ci = i % cin, co = (i / cin) % cop, t = i / (cin * cop);
    pp.cd[0][i] = f2h(pp.cw[0][((size_t)co * cin + ci) * 9 + t]);
  } else if (which <= 4) {
    if (i >= 9 * 80 * 64) return;
    const int cin = 64, cop = 80;
    const int ci = i % cin, co = (i / cin) % cop, t = i / (cin * cop);
    const int g = co / 20, c = co % 20;  // padded slot -> real cout g*18+c
    float v = (c < 18) ? pp.cw[which][((size_t)(g * 18 + c) * cin + ci) * 9 + t]
                       : 0.f;
    pp.cd[which][i] = f2h(v);
  } else if (which <= 8) {
    if (i >= 4 * 5 * 16 * 32) return;
    const int kk = i & 31, o = (i >> 5) & 15, pair = (i >> 9) % 5;
    const int g = i / 2560;
    const int t = pair * 2 + (kk >> 4), c = kk & 15;
    float v = (t < 9) ? pp.dw[which - 5][(size_t)((g * 16 + o) * 16 + c) * 9 + t]
                      : 0.f;
    pp.dd[which - 5][i] = f2h(v);
  } else {
    if (i >= 4 * 80) return;
    const int ten = i / 80, co = i % 80;
    const int g = co / 20, c = co % 20;
    pp.obd[ten][co] = (c < 18) ? pp.ob[ten][g * 18 + c] : 0.f;
  }
}

// ---------------------------------------------------------------------------
// NCHW f32 -> group-split f16: frefG [4][4][pix][16], fmovG [8][4][pix][16]
// ---------------------------------------------------------------------------
__global__ __launch_bounds__(256) void to_gs_kernel(
    const float* __restrict__ Fref, const float* __restrict__ Fm1,
    const float* __restrict__ Fm2, unsigned short* __restrict__ frefG,
    unsigned short* __restrict__ fmovG) {
  const int t = blockIdx.x * 256 + threadIdx.x;  // over BB*NPIX
  const int b2 = t >> 14, pix = t & (NPIX - 1);
  const float* fm = (b2 < 4 ? Fm1 : Fm2) + (size_t)(b2 & 3) * 64 * NPIX + pix;
  for (int c8 = 0; c8 < 8; ++c8) {
    u16x8 v;
#pragma unroll
    for (int j = 0; j < 8; ++j) v[j] = f2h(fm[(size_t)(c8 * 8 + j) * NPIX]);
    *(u16x8*)(fmovG + ((size_t)(b2 * 4 + (c8 >> 1)) * NPIX + pix) * 16 +
              (c8 & 1) * 8) = v;
  }
  if (b2 < 4) {
    const float* fr = Fref + (size_t)b2 * 64 * NPIX + pix;
    for (int c8 = 0; c8 < 8; ++c8) {
      u16x8 v;
#pragma unroll
      for (int j = 0; j < 8; ++j) v[j] = f2h(fr[(size_t)(c8 * 8 + j) * NPIX]);
      *(u16x8*)(frefG + ((size_t)(b2 * 4 + (c8 >> 1)) * NPIX + pix) * 16 +
                (c8 & 1) * 8) = v;
    }
  }
}

// ---------------------------------------------------------------------------
// MFMA conv 3x3 pad 1 (group-split inputs), f16. A-fragments loaded DIRECTLY
// from global per (t,kc) — no weight LDS, no per-tap barriers.
// Used only for the cr conv (CIN=128 -> 64 couts, GS out).
// ---------------------------------------------------------------------------
template <int CIN, int COP, int CO_REAL>
__global__ __launch_bounds__(512, 6) void convmfma_kernel(
    const unsigned short* __restrict__ in0, int bmask0,
    const unsigned short* __restrict__ in1, int bmask1,
    const unsigned short* __restrict__ wT,   // [9][COP][CIN] f16
    const float* __restrict__ biasP,         // [COP]
    unsigned short* __restrict__ out) {      // GS [b][g][pix][16]
  constexpr int COF = COP / 16;
  constexpr int NCH = CIN / 64;
  __shared__ unsigned short sB[324 * 64];

  const int tile = blockIdx.x, b = blockIdx.y;
  const int ty0 = (tile >> 3) << 4, tx0 = (tile & 7) << 4;
  const int tid = threadIdx.x;
  const int wv = tid >> 6, l = tid & 63;
  const int lm = l & 15, lq = l >> 4;

  f32x4 acc[COF][2];
#pragma unroll
  for (int cf = 0; cf < COF; ++cf)
#pragma unroll
    for (int pf = 0; pf < 2; ++pf) acc[cf][pf] = (f32x4){0.f, 0.f, 0.f, 0.f};

  const unsigned short* base0 = in0 + (size_t)(b & bmask0) * 4 * NPIX * 16;
  const unsigned short* base1 =
      (NCH > 1) ? in1 + (size_t)(b & bmask1) * 4 * NPIX * 16 : nullptr;

  for (int ch = 0; ch < NCH; ++ch) {
    const unsigned short* inB = (ch == 0) ? base0 : base1;
    if (ch) __syncthreads();  // prev halo reads done
    for (int q = tid; q < 324 * 8; q += 512) {
      const int pix = q >> 3, ci8 = q & 7;
      const int r = pix / 18, c = pix - r * 18;
      const int gy = ty0 - 1 + r, gx = tx0 - 1 + c;
      u16x8 v;
      if (gy >= 0 && gy < Hh && gx >= 0 && gx < Ww) {
        v = *(const u16x8*)(inB + ((size_t)(ci8 >> 1) * NPIX + gy * Ww + gx) *
                                      16 + (ci8 & 1) * 8);
      } else {
#pragma unroll
        for (int j = 0; j < 8; ++j) v[j] = 0;
      }
      const int boff = pix * 128 + ((ci8 * 16) ^ ((pix & 7) << 4));
      *(u16x8*)((char*)sB + boff) = v;
    }
    __syncthreads();

    // per-lane weight base: this lane's co rows, k-slice lq, chunk ch
    for (int t = 0; t < 9; ++t) {
      const int dy = t / 3, dx = t - dy * 3;
      const unsigned short* wt = wT + (size_t)t * COP * CIN + ch * 64 + lq * 8;
#pragma unroll
      for (int kc = 0; kc < 2; ++kc) {
        f16x8 afr[COF];
#pragma unroll
        for (int cf = 0; cf < COF; ++cf) {
          const int co = cf * 16 + lm;
          afr[cf] = *(const f16x8*)(wt + (size_t)co * CIN + kc * 32);
        }
#pragma unroll
        for (int pf = 0; pf < 2; ++pf) {
          const int pix = wv * 32 + pf * 16 + lm;
          const int spix = ((pix >> 4) + dy) * 18 + (pix & 15) + dx;
          const int boff =
              spix * 128 + ((kc * 64 + lq * 16) ^ ((spix & 7) << 4));
          const f16x8 bfr = *(const f16x8*)((const char*)sB + boff);
#pragma unroll
          for (int cf = 0; cf < COF; ++cf)
            acc[cf][pf] = __builtin_amdgcn_mfma_f32_16x16x32_f16(
                afr[cf], bfr, acc[cf][pf], 0, 0, 0);
        }
      }
    }
  }

#pragma unroll
  for (int cf = 0; cf < COF; ++cf) {
    const int co0 = cf * 16 + lq * 4;
    if (co0 >= CO_REAL) continue;
    const float4 bv = *(const float4*)(biasP + co0);
#pragma unroll
    for (int pf = 0; pf < 2; ++pf) {
      const int pix = wv * 32 + pf * 16 + lm;
      const int gpix = (ty0 + (pix >> 4)) * Ww + tx0 + (pix & 15);
      const f32x4 v = acc[cf][pf];
      ushort4 pk;
      pk.x = f2h(v[0] + bv.x);
      pk.y = f2h(v[1] + bv.y);
      pk.z = f2h(v[2] + bv.z);
      pk.w = f2h(v[3] + bv.w);
      const int gg = co0 >> 4, cc = co0 & 15;
      *(ushort4*)(out + ((size_t)(b * 4 + gg) * NPIX + gpix) * 16 + cc) = pk;
    }
  }
}

// ---------------------------------------------------------------------------
// FUSED off-conv + deform, 4x32 tile, 256 thr (4 waves), 5 blocks/CU.
// Phase 1: conv (A-fragments direct from global; only halo in LDS; 3 barriers
// total) -> sOff LDS [128][168B]. Phase 2: deform (r16).
// LDS 31744: conv {halo [0,26112)} -> deform {sOff [0,21504) | bounce
// [21504,31744)}.
// ---------------------------------------------------------------------------
template <bool NCHW_OUT>
__global__ __launch_bounds__(256, 5) void fused_od_kernel(
    const unsigned short* __restrict__ convIn,  // [b][4][pix][16] f16
    const unsigned short* __restrict__ sampX,   // [b][4][pix][16] f16
    const unsigned short* __restrict__ wT,      // [9][80][64] f16
    const float* __restrict__ obias,            // [80] padded
    const unsigned short* __restrict__ dwP,     // [4][5][16][32] f16
    const float* __restrict__ dbias,            // [64]
    float* __restrict__ outF, unsigned short* __restrict__ outH) {
  __shared__ __attribute__((aligned(16))) char lds[31744];
  char* sB = lds;               // halo: 204 px * 128B = 26112
  char* sOffB = lds;            // [128][168B] = 21504
  char* bounce = lds + 21504;   // [128][80B]  = 10240

  const int tile = blockIdx.x, b = blockIdx.y;
  const int ty0 = (tile >> 2) << 2;   // 32 tile-rows of 4
  const int tx0 = (tile & 3) << 5;    // 4 tile-cols of 32
  const int tid = threadIdx.x;
  const int wv = tid >> 6, l = tid & 63;
  const int lm = l & 15, lq = l >> 4;

  // ================= phase 1: offset conv (CIN=64, COP=80) =================
  f32x4 acc[5][2];
#pragma unroll
  for (int cf = 0; cf < 5; ++cf)
#pragma unroll
    for (int pf = 0; pf < 2; ++pf) acc[cf][pf] = (f32x4){0.f, 0.f, 0.f, 0.f};

  const unsigned short* inB = convIn + (size_t)b * 4 * NPIX * 16;

  // stage halo: 6 rows x 34 cols = 204 px x 8 ci8
  for (int q = tid; q < 204 * 8; q += 256) {
    const int pix = q >> 3, ci8 = q & 7;
    const int r = pix / 34, c = pix - r * 34;
    const int gy = ty0 - 1 + r, gx = tx0 - 1 + c;
    u16x8 v;
    if (gy >= 0 && gy < Hh && gx >= 0 && gx < Ww) {
      v = *(const u16x8*)(inB + ((size_t)(ci8 >> 1) * NPIX + gy * Ww + gx) *
                                    16 + (ci8 & 1) * 8);
    } else {
#pragma unroll
      for (int j = 0; j < 8; ++j) v[j] = 0;
    }
    const int boff = pix * 128 + ((ci8 * 16) ^ ((pix & 7) << 4));
    *(u16x8*)(sB + boff) = v;
  }
  __syncthreads();

  // 9 taps, no barriers: A-fragments direct from global (L1-resident)
  for (int t = 0; t < 9; ++t) {
    const int dy = t / 3, dx = t - dy * 3;
    const unsigned short* wt = wT + (size_t)t * 5120 + lq * 8;
#pragma unroll
    for (int kc = 0; kc < 2; ++kc) {
      f16x8 afr[5];
#pragma unroll
      for (int cf = 0; cf < 5; ++cf) {
        const int co = cf * 16 + lm;
        afr[cf] = *(const f16x8*)(wt + (size_t)co * 64 + kc * 32);
      }
#pragma unroll
      for (int pf = 0; pf < 2; ++pf) {
        const int pix = wv * 32 + pf * 16 + lm;
        const int spix = ((pix >> 5) + dy) * 34 + (pix & 31) + dx;
        const int boff = spix * 128 + ((kc * 64 + lq * 16) ^ ((spix & 7) << 4));
        const f16x8 bfr = *(const f16x8*)(sB + boff);
#pragma unroll
        for (int cf = 0; cf < 5; ++cf)
          acc[cf][pf] = __builtin_amdgcn_mfma_f32_16x16x32_f16(
              afr[cf], bfr, acc[cf][pf], 0, 0, 0);
      }
    }
  }
  __syncthreads();  // halo reads done; sOff may now alias it

  // epilogue -> sOff [128][168B]
#pragma unroll
  for (int cf = 0; cf < 5; ++cf) {
    const int co0 = cf * 16 + lq * 4;
    const float4 bv = *(const float4*)(obias + co0);
#pragma unroll
    for (int pf = 0; pf < 2; ++pf) {
      const int pix = wv * 32 + pf * 16 + lm;
      const f32x4 v = acc[cf][pf];
      ushort4 pk;
      pk.x = f2h(v[0] + bv.x);
      pk.y = f2h(v[1] + bv.y);
      pk.z = f2h(v[2] + bv.z);
      pk.w = f2h(v[3] + bv.w);
      *(ushort4*)(sOffB + pix * 168 + co0 * 2) = pk;
    }
  }
  __syncthreads();

  // ================= phase 2: deform (4 groups per thread) =================
  const int p = tid >> 1, h = tid & 1;  // pixel 0..127, channel-half
  const int y = ty0 + (p >> 5), xx = tx0 + (p & 31);
  char* myB = bounce + p * 80 + h * 16;

  for (int g = 0; g < 4; ++g) {
    const unsigned short* xP =
        sampX + (size_t)(b * 4 + g) * NPIX * 16 + h * 8;
    unsigned od[9];
#pragma unroll
    for (int t = 0; t < 9; ++t)
      od[t] = *(const unsigned*)(sOffB + p * 168 + (g * 20 + 2 * t) * 2);

    f16x8 afr[5];
#pragma unroll
    for (int pr = 0; pr < 5; ++pr)
      afr[pr] = *(const f16x8*)(dwP + ((size_t)(g * 5 + pr) * 16 + lm) * 32 +
                                lq * 8);

    f32x4 dacc[2];
    dacc[0] = (f32x4){0.f, 0.f, 0.f, 0.f};
    dacc[1] = (f32x4){0.f, 0.f, 0.f, 0.f};

#pragma unroll
    for (int pair = 0; pair < 5; ++pair) {
#pragma unroll
      for (int ti = 0; ti < 2; ++ti) {
        const int t = pair * 2 + ti;
        uint4 sv = (uint4){0u, 0u, 0u, 0u};
        if (t < 9) {
          const unsigned odw = od[t];
          const f16* op = (const f16*)&odw;
          const float dy = (float)op[0];
          const float dx = (float)op[1];
          const float py = dy + (float)(y - 2 + 2 * (t / 3));
          const float px = dx + (float)(xx - 2 + 2 * (t % 3));
          const float fy = floorf(py), fx = floorf(px);
          const int y0 = (int)fy, x0 = (int)fx;
          const int y1 = y0 + 1, x1 = x0 + 1;
          const float ly = py - fy, lx = px - fx;
          float w00 = (1.f - ly) * (1.f - lx), w01 = (1.f - ly) * lx;
          float w10 = ly * (1.f - lx), w11 = ly * lx;
          const bool vy0 = (y0 >= 0) && (y0 < Hh), vy1 = (y1 >= 0) && (y1 < Hh);
          const bool vx0 = (x0 >= 0) && (x0 < Ww), vx1 = (x1 >= 0) && (x1 < Ww);
          w00 = (vy0 && vx0) ? w00 : 0.f;
          w01 = (vy0 && vx1) ? w01 : 0.f;
          w10 = (vy1 && vx0) ? w10 : 0.f;
          w11 = (vy1 && vx1) ? w11 : 0.f;
          const int y0c = min(max(y0, 0), Hh - 1), y1c = min(max(y1, 0), Hh - 1);
          const int x0c = min(max(x0, 0), Ww - 1), x1c = min(max(x1, 0), Ww - 1);
          const u16x8 a00 = *(const u16x8*)(xP + (size_t)(y0c * Ww + x0c) * 16);
          const u16x8 a01 = *(const u16x8*)(xP + (size_t)(y0c * Ww + x1c) * 16);
          const u16x8 a10 = *(const u16x8*)(xP + (size_t)(y1c * Ww + x0c) * 16);
          const u16x8 a11 = *(const u16x8*)(xP + (size_t)(y1c * Ww + x1c) * 16);
          const h2* c00 = (const h2*)&a00;
          const h2* c01 = (const h2*)&a01;
          const h2* c10 = (const h2*)&a10;
          const h2* c11 = (const h2*)&a11;
          const f16 h00 = (f16)w00, h01 = (f16)w01;
          const f16 h10 = (f16)w10, h11 = (f16)w11;
          const h2 p00 = (h2){h00, h00}, p01 = (h2){h01, h01};
          const h2 p10 = (h2){h10, h10}, p11 = (h2){h11, h11};
          unsigned fw[4];
#pragma unroll
          for (int j = 0; j < 4; ++j) {
            h2 r = c00[j] * p00;
            r += c01[j] * p01;
            r += c10[j] * p10;
            r += c11[j] * p11;
            fw[j] = *(const unsigned*)&r;
          }
          sv = (uint4){fw[0], fw[1], fw[2], fw[3]};
        }
        *(uint4*)(myB + ti * 32) = sv;
      }
#pragma unroll
      for (int n = 0; n < 2; ++n) {
        const f16x8 bfr =
            *(const f16x8*)(bounce + (wv * 32 + n * 16 + lm) * 80 + lq * 16);
        dacc[n] = __builtin_amdgcn_mfma_f32_16x16x32_f16(afr[pair], bfr,
                                                         dacc[n], 0, 0, 0);
      }
    }

    const float4 bv = *(const float4*)(dbias + g * 16 + lq * 4);
#pragma unroll
    for (int n = 0; n < 2; ++n) {
      const int pixl = wv * 32 + n * 16 + lm;
      const int gpix = (ty0 + (pixl >> 5)) * Ww + tx0 + (pixl & 31);
      const f32x4 v = dacc[n];
      if (NCHW_OUT) {
        float* oB = outF + (size_t)(b * 64 + g * 16 + lq * 4) * NPIX + gpix;
        oB[0] = v[0] + bv.x;
        oB[NPIX] = v[1] + bv.y;
        oB[2 * NPIX] = v[2] + bv.z;
        oB[3 * NPIX] = v[3] + bv.w;
      } else {
        ushort4 pk;
        pk.x = f2h(v[0] + bv.x);
        pk.y = f2h(v[1] + bv.y);
        pk.z = f2h(v[2] + bv.z);
        pk.w = f2h(v[3] + bv.w);
        *(ushort4*)(outH + ((size_t)(b * 4 + g) * NPIX + gpix) * 16 + lq * 4) =
            pk;
      }
    }
  }
}

// ---------------------------------------------------------------------------

extern "C" void kernel_launch(void* const* d_in, const int* in_sizes, int n_in,
                              void* d_out, int out_size, void* d_ws,
                              size_t ws_size, hipStream_t stream) {
  const float* Fref = (const float*)d_in[0];
  const float* Fmov1 = (const float*)d_in[1];
  const float* Fmov2 = (const float*)d_in[2];
  const float* cr_w = (const float*)d_in[3];
  const float* cr_b = (const float*)d_in[4];
  const float* offw[4] = {(const float*)d_in[5], (const float*)d_in[7],
                          (const float*)d_in[9], (const float*)d_in[11]};
  const float* offb[4] = {(const float*)d_in[6], (const float*)d_in[8],
                          (const float*)d_in[10], (const float*)d_in[12]};
  const float* dw[4] = {(const float*)d_in[13], (const float*)d_in[15],
                        (const float*)d_in[17], (const float*)d_in[19]};
  const float* db[4] = {(const float*)d_in[14], (const float*)d_in[16],
                        (const float*)d_in[18], (const float*)d_in[20]};

  char* p = (char*)d_ws;
  auto carve = [&](size_t bytes) {
    void* r = p;
    p += (bytes + 255) & ~(size_t)255;
    return r;
  };
  unsigned short* frefG = (unsigned short*)carve((size_t)4 * 4 * NPIX * 16 * 2);
  unsigned short* fmovG = (unsigned short*)carve((size_t)BB * 4 * NPIX * 16 * 2);
  unsigned short* feaA = (unsigned short*)carve((size_t)BB * 4 * NPIX * 16 * 2);
  unsigned short* feaB = (unsigned short*)carve((size_t)BB * 4 * NPIX * 16 * 2);
  unsigned short* wcrT = (unsigned short*)carve((size_t)9 * 64 * 128 * 2);
  unsigned short* woffT[4];
  for (int i = 0; i < 4; ++i)
    woffT[i] = (unsigned short*)carve((size_t)9 * 80 * 64 * 2);
  unsigned short* dwP[4];
  for (int i = 0; i < 4; ++i)
    dwP[i] = (unsigned short*)carve((size_t)4 * 5 * 16 * 32 * 2);
  float* obP[4];
  for (int i = 0; i < 4; ++i) obP[i] = (float*)carve((size_t)80 * 4);

  PrepPtrs pp;
  pp.cw[0] = cr_w;
  pp.cd[0] = wcrT;
  for (int i = 0; i < 4; ++i) {
    pp.cw[i + 1] = offw[i];
    pp.cd[i + 1] = woffT[i];
    pp.dw[i] = dw[i];
    pp.dd[i] = dwP[i];
    pp.ob[i] = offb[i];
    pp.obd[i] = obP[i];
  }
  prep_all_kernel<<<dim3(288, 10), 256, 0, stream>>>(pp);

  to_gs_kernel<<<BB * NPIX / 256, 256, 0, stream>>>(Fref, Fmov1, Fmov2, frefG,
                                                    fmovG);

  const dim3 cgrid(64, BB), cblk(512);
  const dim3 fgrid(128, BB), fblk(256);
  float* outF = (float*)d_out;  // [b2][64][H][W], b2 0-3 = branch1, 4-7 = br2

  // fea = conv([Fref|Fmov], cr)                    -> feaA (GS)
  convmfma_kernel<128, 64, 64><<<cgrid, cblk, 0, stream>>>(
      frefG, 3, fmovG, 7, wcrT, cr_b, feaA);
  // fused: off1 = conv(feaA); fea = deform(feaA)   -> feaB
  fused_od_kernel<false><<<fgrid, fblk, 0, stream>>>(
      feaA, feaA, woffT[0], obP[0], dwP[0], db[0], nullptr, feaB);
  // fused: off2 = conv(feaB); fea = deform(feaB)   -> feaA
  fused_od_kernel<false><<<fgrid, fblk, 0, stream>>>(
      feaB, feaB, woffT[1], obP[1], dwP[1], db[1], nullptr, feaA);
  // fused: off3 = conv(feaA); fea = deform(fmovG)  -> feaB
  fused_od_kernel<false><<<fgrid, fblk, 0, stream>>>(
      feaA, fmovG, woffT[2], obP[2], dwP[2], db[2], nullptr, feaB);
  // fused: off4 = conv(feaB); out = deform(feaB)   -> d_out (f32 NCHW)
  fused_od_kernel<true><<<fgrid, fblk, 0, stream>>>(
      feaB, feaB, woffT[3], obP[3], dwP[3], db[3], outF, nullptr);
}

// Round 18
// 229.009 us; speedup vs baseline: 1.9198x; 1.9198x over previous
//
#include <hip/hip_runtime.h>

// AlignmentNet round 18: exact round-16 structure (best measured, 235.7us)
// + XCD-aware bijective block swizzle on the tile dimension (grid x % 8 == 0)
// so each tile-chunk pins to one XCD's L2 across ALL layers (inter-layer
// fea reuse + intra-layer halo/window sharing).

using f16   = _Float16;
using f16x8 = __attribute__((ext_vector_type(8))) f16;
using h2    = __attribute__((ext_vector_type(2))) f16;
using u16x8 = __attribute__((ext_vector_type(8))) unsigned short;
using f32x4 = __attribute__((ext_vector_type(4))) float;

static constexpr int Hh = 128, Ww = 128, NB = 4, NPIX = Hh * Ww;
static constexpr int BB = 8;  // batch*branches

__device__ __forceinline__ unsigned short f2h(float f) {
  f16 h = (f16)f;
  return *(unsigned short*)&h;
}

// ---------------------------------------------------------------------------
// Fused weight prep. which: 0=cr, 1-4=off convs (cout padded 18->20 per g),
// 5-8=deform w, 9=off biases (padded to [80] in g*20+c layout).
// ---------------------------------------------------------------------------
struct PrepPtrs {
  const float* cw[5];
  unsigned short* cd[5];
  const float* dw[4];
  unsigned short* dd[4];
  const float* ob[4];
  float* obd[4];
};

__global__ __launch_bounds__(256) void prep_all_kernel(PrepPtrs pp) {
  const int which = blockIdx.y;
  const int i = blockIdx.x * 256 + threadIdx.x;
  if (which == 0) {
    if (i >= 9 * 64 * 128) return;
    const int cin = 128, cop = 64;
    const int ci = i % cin, co = (i / cin) % cop, t = i / (cin * cop);
    pp.cd[0][i] = f2h(pp.cw[0][((size_t)co * cin + ci) * 9 + t]);
  } else if (which <= 4) {
    if (i >= 9 * 80 * 64) return;
    const int cin = 64, cop = 80;
    const int ci = i % cin, co = (i / cin) % cop, t = i / (cin * cop);
    const int g = co / 20, c = co % 20;  // padded slot -> real cout g*18+c
    float v = (c < 18) ? pp.cw[which][((size_t)(g * 18 + c) * cin + ci) * 9 + t]
                       : 0.f;
    pp.cd[which][i] = f2h(v);
  } else if (which <= 8) {
    if (i >= 4 * 5 * 16 * 32) return;
    const int kk = i & 31, o = (i >> 5) & 15, pair = (i >> 9) % 5;
    const int g = i / 2560;
    const int t = pair * 2 + (kk >> 4), c = kk & 15;
    float v = (t < 9) ? pp.dw[which - 5][(size_t)((g * 16 + o) * 16 + c) * 9 + t]
                      : 0.f;
    pp.dd[which - 5][i] = f2h(v);
  } else {
    if (i >= 4 * 80) return;
    const int ten = i / 80, co = i % 80;
    const int g = co / 20, c = co % 20;
    pp.obd[ten][co] = (c < 18) ? pp.ob[ten][g * 18 + c] : 0.f;
  }
}

// ---------------------------------------------------------------------------
// NCHW f32 -> group-split f16: frefG [4][4][pix][16], fmovG [8][4][pix][16]
// ---------------------------------------------------------------------------
__global__ __launch_bounds__(256) void to_gs_kernel(
    const float* __restrict__ Fref, const float* __restrict__ Fm1,
    const float* __restrict__ Fm2, unsigned short* __restrict__ frefG,
    unsigned short* __restrict__ fmovG) {
  const int t = blockIdx.x * 256 + threadIdx.x;  // over BB*NPIX
  const int b2 = t >> 14, pix = t & (NPIX - 1);
  const float* fm = (b2 < 4 ? Fm1 : Fm2) + (size_t)(b2 & 3) * 64 * NPIX + pix;
  for (int c8 = 0; c8 < 8; ++c8) {
    u16x8 v;
#pragma unroll
    for (int j = 0; j < 8; ++j) v[j] = f2h(fm[(size_t)(c8 * 8 + j) * NPIX]);
    *(u16x8*)(fmovG + ((size_t)(b2 * 4 + (c8 >> 1)) * NPIX + pix) * 16 +
              (c8 & 1) * 8) = v;
  }
  if (b2 < 4) {
    const float* fr = Fref + (size_t)b2 * 64 * NPIX + pix;
    for (int c8 = 0; c8 < 8; ++c8) {
      u16x8 v;
#pragma unroll
      for (int j = 0; j < 8; ++j) v[j] = f2h(fr[(size_t)(c8 * 8 + j) * NPIX]);
      *(u16x8*)(frefG + ((size_t)(b2 * 4 + (c8 >> 1)) * NPIX + pix) * 16 +
                (c8 & 1) * 8) = v;
    }
  }
}

// ---------------------------------------------------------------------------
// MFMA conv 3x3 pad 1 (group-split inputs), f16. Per-tap weight ring.
// Used only for the cr conv (CIN=128 -> 64 couts, GS out). (round 15/16)
// Tile index XCD-swizzled: 64 tiles, chunk 8.
// ---------------------------------------------------------------------------
template <int CIN, int COP, int CO_REAL>
__global__ __launch_bounds__(512, 2) void convmfma_kernel(
    const unsigned short* __restrict__ in0, int bmask0,
    const unsigned short* __restrict__ in1, int bmask1,
    const unsigned short* __restrict__ wT,   // [9][COP][CIN] f16
    const float* __restrict__ biasP,         // [COP]
    unsigned short* __restrict__ out) {      // GS [b][g][pix][16]
  constexpr int COF = COP / 16;
  constexpr int NCH = CIN / 64;
  constexpr int NT = NCH * 9;
  __shared__ unsigned short sW[2][COP * 64];
  __shared__ unsigned short sB[324 * 64];

  const int tile = ((blockIdx.x & 7) << 3) | (blockIdx.x >> 3);  // XCD swizzle
  const int b = blockIdx.y;
  const int ty0 = (tile >> 3) << 4, tx0 = (tile & 7) << 4;
  const int tid = threadIdx.x;
  const int wv = tid >> 6, l = tid & 63;
  const int lm = l & 15, lq = l >> 4;

  f32x4 acc[COF][2];
#pragma unroll
  for (int cf = 0; cf < COF; ++cf)
#pragma unroll
    for (int pf = 0; pf < 2; ++pf) acc[cf][pf] = (f32x4){0.f, 0.f, 0.f, 0.f};

  const unsigned short* base0 = in0 + (size_t)(b & bmask0) * 4 * NPIX * 16;
  const unsigned short* base1 =
      (NCH > 1) ? in1 + (size_t)(b & bmask1) * 4 * NPIX * 16 : nullptr;

  auto stage_input = [&](int ch) {
    const unsigned short* inB = (ch == 0) ? base0 : base1;
    for (int q = tid; q < 324 * 8; q += 512) {
      const int pix = q >> 3, ci8 = q & 7;
      const int r = pix / 18, c = pix - r * 18;
      const int gy = ty0 - 1 + r, gx = tx0 - 1 + c;
      u16x8 v;
      if (gy >= 0 && gy < Hh && gx >= 0 && gx < Ww) {
        v = *(const u16x8*)(inB + ((size_t)(ci8 >> 1) * NPIX + gy * Ww + gx) *
                                      16 + (ci8 & 1) * 8);
      } else {
#pragma unroll
        for (int j = 0; j < 8; ++j) v[j] = 0;
      }
      const int boff = pix * 128 + ((ci8 * 16) ^ ((pix & 7) << 4));
      *(u16x8*)((char*)sB + boff) = v;
    }
  };
  auto stage_w = [&](int tt, int buf) {
    const int ch = tt / 9, t = tt - ch * 9;
    for (int q = tid; q < COP * 8; q += 512) {
      const int ci8 = q & 7;
      const int co = q >> 3;
      u16x8 v = *(const u16x8*)(wT + (size_t)(t * COP + co) * CIN + ch * 64 +
                                ci8 * 8);
      const int aoff = co * 128 + ((ci8 * 16) ^ ((co & 7) << 4));
      *(u16x8*)((char*)sW[buf] + aoff) = v;
    }
  };

  stage_input(0);
  stage_w(0, 0);
  __syncthreads();

  for (int tt = 0; tt < NT; ++tt) {
    const int t = tt % 9;
    const bool nextNewCh = ((tt + 1) % 9 == 0);
    if (tt + 1 < NT && !nextNewCh) stage_w(tt + 1, (tt + 1) & 1);

    const int dy = t / 3, dx = t - dy * 3;
    const char* sWc = (const char*)sW[tt & 1];
#pragma unroll
    for (int kc = 0; kc < 2; ++kc) {
      f16x8 afr[COF];
#pragma unroll
      for (int cf = 0; cf < COF; ++cf) {
        const int co = cf * 16 + lm;
        const int aoff = co * 128 + ((kc * 64 + lq * 16) ^ ((co & 7) << 4));
        afr[cf] = *(const f16x8*)(sWc + aoff);
      }
#pragma unroll
      for (int pf = 0; pf < 2; ++pf) {
        const int pix = wv * 32 + pf * 16 + lm;
        const int spix = ((pix >> 4) + dy) * 18 + (pix & 15) + dx;
        const int boff = spix * 128 + ((kc * 64 + lq * 16) ^ ((spix & 7) << 4));
        const f16x8 bfr = *(const f16x8*)((const char*)sB + boff);
#pragma unroll
        for (int cf = 0; cf < COF; ++cf)
          acc[cf][pf] = __builtin_amdgcn_mfma_f32_16x16x32_f16(
              afr[cf], bfr, acc[cf][pf], 0, 0, 0);
      }
    }
    __syncthreads();
    if (tt + 1 < NT && nextNewCh) {
      stage_input((tt + 1) / 9);
      stage_w(tt + 1, (tt + 1) & 1);
      __syncthreads();
    }
  }

#pragma unroll
  for (int cf = 0; cf < COF; ++cf) {
    const int co0 = cf * 16 + lq * 4;
    if (co0 >= CO_REAL) continue;
    const float4 bv = *(const float4*)(biasP + co0);
#pragma unroll
    for (int pf = 0; pf < 2; ++pf) {
      const int pix = wv * 32 + pf * 16 + lm;
      const int gpix = (ty0 + (pix >> 4)) * Ww + tx0 + (pix & 15);
      const f32x4 v = acc[cf][pf];
      ushort4 pk;
      pk.x = f2h(v[0] + bv.x);
      pk.y = f2h(v[1] + bv.y);
      pk.z = f2h(v[2] + bv.z);
      pk.w = f2h(v[3] + bv.w);
      const int gg = co0 >> 4, cc = co0 & 15;
      *(ushort4*)(out + ((size_t)(b * 4 + gg) * NPIX + gpix) * 16 + cc) = pk;
    }
  }
}

// ---------------------------------------------------------------------------
// FUSED off-conv + deform, 4x32 tile, 256 thr (4 waves), 4 blocks/CU.
// Phase 1: conv -> 80 offset couts -> sOff LDS [128][168B].
// Phase 2: deform (4 groups serial), packed-half2 interp, LDS bounce.
// LDS: [0,26112) halo | [26112,36352) sW  ->  [0,21504) sOff | [26112,36352)
// bounce. Weights single-buffered with register prefetch.
// Tile index XCD-swizzled: 128 tiles, chunk 16.
// ---------------------------------------------------------------------------
template <bool NCHW_OUT>
__global__ __launch_bounds__(256, 4) void fused_od_kernel(
    const unsigned short* __restrict__ convIn,  // [b][4][pix][16] f16
    const unsigned short* __restrict__ sampX,   // [b][4][pix][16] f16
    const unsigned short* __restrict__ wT,      // [9][80][64] f16
    const float* __restrict__ obias,            // [80] padded
    const unsigned short* __restrict__ dwP,     // [4][5][16][32] f16
    const float* __restrict__ dbias,            // [64]
    float* __restrict__ outF, unsigned short* __restrict__ outH) {
  __shared__ __attribute__((aligned(16))) char lds[36352];
  char* sB = lds;               // halo: 204 px * 128B
  char* sW = lds + 26112;       // 80 co * 128B
  char* sOffB = lds;            // [128][168B]
  char* bounce = lds + 26112;   // [128][80B]

  const int tile = ((blockIdx.x & 7) << 4) | (blockIdx.x >> 3);  // XCD swizzle
  const int b = blockIdx.y;
  const int ty0 = (tile >> 2) << 2;   // 32 tile-rows of 4
  const int tx0 = (tile & 3) << 5;    // 4 tile-cols of 32
  const int tid = threadIdx.x;
  const int wv = tid >> 6, l = tid & 63;
  const int lm = l & 15, lq = l >> 4;

  // ================= phase 1: offset conv (CIN=64, COP=80) =================
  f32x4 acc[5][2];
#pragma unroll
  for (int cf = 0; cf < 5; ++cf)
#pragma unroll
    for (int pf = 0; pf < 2; ++pf) acc[cf][pf] = (f32x4){0.f, 0.f, 0.f, 0.f};

  const unsigned short* inB = convIn + (size_t)b * 4 * NPIX * 16;

  // weight reg-prefetch: 640 u16x8 per tap
  u16x8 wr0, wr1, wr2;
  auto wload = [&](int t) {
    const unsigned short* wt = wT + (size_t)t * 5120;
    wr0 = *(const u16x8*)(wt + (size_t)(tid >> 3) * 64 + (tid & 7) * 8);
    const int q1 = tid + 256;
    wr1 = *(const u16x8*)(wt + (size_t)(q1 >> 3) * 64 + (q1 & 7) * 8);
    if (tid < 128) {
      const int q2 = tid + 512;
      wr2 = *(const u16x8*)(wt + (size_t)(q2 >> 3) * 64 + (q2 & 7) * 8);
    }
  };
  auto wstore = [&]() {
    auto put = [&](int q, u16x8 v) {
      const int co = q >> 3, ci8 = q & 7;
      *(u16x8*)(sW + co * 128 + ((ci8 * 16) ^ ((co & 7) << 4))) = v;
    };
    put(tid, wr0);
    put(tid + 256, wr1);
    if (tid < 128) put(tid + 512, wr2);
  };

  wload(0);
  // stage halo: 6 rows x 34 cols = 204 px x 8 ci8
  for (int q = tid; q < 204 * 8; q += 256) {
    const int pix = q >> 3, ci8 = q & 7;
    const int r = pix / 34, c = pix - r * 34;
    const int gy = ty0 - 1 + r, gx = tx0 - 1 + c;
    u16x8 v;
    if (gy >= 0 && gy < Hh && gx >= 0 && gx < Ww) {
      v = *(const u16x8*)(inB + ((size_t)(ci8 >> 1) * NPIX + gy * Ww + gx) *
                                    16 + (ci8 & 1) * 8);
    } else {
#pragma unroll
      for (int j = 0; j < 8; ++j) v[j] = 0;
    }
    const int boff = pix * 128 + ((ci8 * 16) ^ ((pix & 7) << 4));
    *(u16x8*)(sB + boff) = v;
  }
  wstore();
  __syncthreads();

  for (int t = 0; t < 9; ++t) {
    if (t + 1 < 9) wload(t + 1);  // loads in flight during mfma(t)
    const int dy = t / 3, dx = t - dy * 3;
#pragma unroll
    for (int kc = 0; kc < 2; ++kc) {
      f16x8 afr[5];
#pragma unroll
      for (int cf = 0; cf < 5; ++cf) {
        const int co = cf * 16 + lm;
        const int aoff = co * 128 + ((kc * 64 + lq * 16) ^ ((co & 7) << 4));
        afr[cf] = *(const f16x8*)(sW + aoff);
      }
#pragma unroll
      for (int pf = 0; pf < 2; ++pf) {
        const int pix = wv * 32 + pf * 16 + lm;
        const int spix = ((pix >> 5) + dy) * 34 + (pix & 31) + dx;
        const int boff = spix * 128 + ((kc * 64 + lq * 16) ^ ((spix & 7) << 4));
        const f16x8 bfr = *(const f16x8*)(sB + boff);
#pragma unroll
        for (int cf = 0; cf < 5; ++cf)
          acc[cf][pf] = __builtin_amdgcn_mfma_f32_16x16x32_f16(
              afr[cf], bfr, acc[cf][pf], 0, 0, 0);
      }
    }
    __syncthreads();  // all sW reads done
    if (t + 1 < 9) {
      wstore();
      __syncthreads();  // sW ready
    }
  }

  // epilogue -> sOff [128][168B] (aliases halo; conv reads all done)
#pragma unroll
  for (int cf = 0; cf < 5; ++cf) {
    const int co0 = cf * 16 + lq * 4;
    const float4 bv = *(const float4*)(obias + co0);
#pragma unroll
    for (int pf = 0; pf < 2; ++pf) {
      const int pix = wv * 32 + pf * 16 + lm;
      const f32x4 v = acc[cf][pf];
      ushort4 pk;
      pk.x = f2h(v[0] + bv.x);
      pk.y = f2h(v[1] + bv.y);
      pk.z = f2h(v[2] + bv.z);
      pk.w = f2h(v[3] + bv.w);
      *(ushort4*)(sOffB + pix * 168 + co0 * 2) = pk;
    }
  }
  __syncthreads();

  // ================= phase 2: deform (4 groups per thread) =================
  const int p = tid >> 1, h = tid & 1;  // pixel 0..127, channel-half
  const int y = ty0 + (p >> 5), xx = tx0 + (p & 31);
  char* myB = bounce + p * 80 + h * 16;

  for (int g = 0; g < 4; ++g) {
    const unsigned short* xP =
        sampX + (size_t)(b * 4 + g) * NPIX * 16 + h * 8;
    unsigned od[9];
#pragma unroll
    for (int t = 0; t < 9; ++t)
      od[t] = *(const unsigned*)(sOffB + p * 168 + (g * 20 + 2 * t) * 2);

    f16x8 afr[5];
#pragma unroll
    for (int pr = 0; pr < 5; ++pr)
      afr[pr] = *(const f16x8*)(dwP + ((size_t)(g * 5 + pr) * 16 + lm) * 32 +
                                lq * 8);

    f32x4 dacc[2];
    dacc[0] = (f32x4){0.f, 0.f, 0.f, 0.f};
    dacc[1] = (f32x4){0.f, 0.f, 0.f, 0.f};

#pragma unroll
    for (int pair = 0; pair < 5; ++pair) {
#pragma unroll
      for (int ti = 0; ti < 2; ++ti) {
        const int t = pair * 2 + ti;
        uint4 sv = (uint4){0u, 0u, 0u, 0u};
        if (t < 9) {
          const unsigned odw = od[t];
          const f16* op = (const f16*)&odw;
          const float dy = (float)op[0];
          const float dx = (float)op[1];
          const float py = dy + (float)(y - 2 + 2 * (t / 3));
          const float px = dx + (float)(xx - 2 + 2 * (t % 3));
          const float fy = floorf(py), fx = floorf(px);
          const int y0 = (int)fy, x0 = (int)fx;
          const int y1 = y0 + 1, x1 = x0 + 1;
          const float ly = py - fy, lx = px - fx;
          float w00 = (1.f - ly) * (1.f - lx), w01 = (1.f - ly) * lx;
          float w10 = ly * (1.f - lx), w11 = ly * lx;
          const bool vy0 = (y0 >= 0) && (y0 < Hh), vy1 = (y1 >= 0) && (y1 < Hh);
          const bool vx0 = (x0 >= 0) && (x0 < Ww), vx1 = (x1 >= 0) && (x1 < Ww);
          w00 = (vy0 && vx0) ? w00 : 0.f;
          w01 = (vy0 && vx1) ? w01 : 0.f;
          w10 = (vy1 && vx0) ? w10 : 0.f;
          w11 = (vy1 && vx1) ? w11 : 0.f;
          const int y0c = min(max(y0, 0), Hh - 1), y1c = min(max(y1, 0), Hh - 1);
          const int x0c = min(max(x0, 0), Ww - 1), x1c = min(max(x1, 0), Ww - 1);
          const u16x8 a00 = *(const u16x8*)(xP + (size_t)(y0c * Ww + x0c) * 16);
          const u16x8 a01 = *(const u16x8*)(xP + (size_t)(y0c * Ww + x1c) * 16);
          const u16x8 a10 = *(const u16x8*)(xP + (size_t)(y1c * Ww + x0c) * 16);
          const u16x8 a11 = *(const u16x8*)(xP + (size_t)(y1c * Ww + x1c) * 16);
          const h2* c00 = (const h2*)&a00;
          const h2* c01 = (const h2*)&a01;
          const h2* c10 = (const h2*)&a10;
          const h2* c11 = (const h2*)&a11;
          const f16 h00 = (f16)w00, h01 = (f16)w01;
          const f16 h10 = (f16)w10, h11 = (f16)w11;
          const h2 p00 = (h2){h00, h00}, p01 = (h2){h01, h01};
          const h2 p10 = (h2){h10, h10}, p11 = (h2){h11, h11};
          unsigned fw[4];
#pragma unroll
          for (int j = 0; j < 4; ++j) {
            h2 r = c00[j] * p00;
            r += c01[j] * p01;
            r += c10[j] * p10;
            r += c11[j] * p11;
            fw[j] = *(const unsigned*)&r;
          }
          sv = (uint4){fw[0], fw[1], fw[2], fw[3]};
        }
        *(uint4*)(myB + ti * 32) = sv;
      }
#pragma unroll
      for (int n = 0; n < 2; ++n) {
        const f16x8 bfr =
            *(const f16x8*)(bounce + (wv * 32 + n * 16 + lm) * 80 + lq * 16);
        dacc[n] = __builtin_amdgcn_mfma_f32_16x16x32_f16(afr[pair], bfr,
                                                         dacc[n], 0, 0, 0);
      }
    }

    const float4 bv = *(const float4*)(dbias + g * 16 + lq * 4);
#pragma unroll
    for (int n = 0; n < 2; ++n) {
      const int pixl = wv * 32 + n * 16 + lm;
      const int gpix = (ty0 + (pixl >> 5)) * Ww + tx0 + (pixl & 31);
      const f32x4 v = dacc[n];
      if (NCHW_OUT) {
        float* oB = outF + (size_t)(b * 64 + g * 16 + lq * 4) * NPIX + gpix;
        oB[0] = v[0] + bv.x;
        oB[NPIX] = v[1] + bv.y;
        oB[2 * NPIX] = v[2] + bv.z;
        oB[3 * NPIX] = v[3] + bv.w;
      } else {
        ushort4 pk;
        pk.x = f2h(v[0] + bv.x);
        pk.y = f2h(v[1] + bv.y);
        pk.z = f2h(v[2] + bv.z);
        pk.w = f2h(v[3] + bv.w);
        *(ushort4*)(outH + ((size_t)(b * 4 + g) * NPIX + gpix) * 16 + lq * 4) =
            pk;
      }
    }
  }
}

// ---------------------------------------------------------------------------

extern "C" void kernel_launch(void* const* d_in, const int* in_sizes, int n_in,
                              void* d_out, int out_size, void* d_ws,
                              size_t ws_size, hipStream_t stream) {
  const float* Fref = (const float*)d_in[0];
  const float* Fmov1 = (const float*)d_in[1];
  const float* Fmov2 = (const float*)d_in[2];
  const float* cr_w = (const float*)d_in[3];
  const float* cr_b = (const float*)d_in[4];
  const float* offw[4] = {(const float*)d_in[5], (const float*)d_in[7],
                          (const float*)d_in[9], (const float*)d_in[11]};
  const float* offb[4] = {(const float*)d_in[6], (const float*)d_in[8],
                          (const float*)d_in[10], (const float*)d_in[12]};
  const float* dw[4] = {(const float*)d_in[13], (const float*)d_in[15],
                        (const float*)d_in[17], (const float*)d_in[19]};
  const float* db[4] = {(const float*)d_in[14], (const float*)d_in[16],
                        (const float*)d_in[18], (const float*)d_in[20]};

  char* p = (char*)d_ws;
  auto carve = [&](size_t bytes) {
    void* r = p;
    p += (bytes + 255) & ~(size_t)255;
    return r;
  };
  unsigned short* frefG = (unsigned short*)carve((size_t)4 * 4 * NPIX * 16 * 2);
  unsigned short* fmovG = (unsigned short*)carve((size_t)BB * 4 * NPIX * 16 * 2);
  unsigned short* feaA = (unsigned short*)carve((size_t)BB * 4 * NPIX * 16 * 2);
  unsigned short* feaB = (unsigned short*)carve((size_t)BB * 4 * NPIX * 16 * 2);
  unsigned short* wcrT = (unsigned short*)carve((size_t)9 * 64 * 128 * 2);
  unsigned short* woffT[4];
  for (int i = 0; i < 4; ++i)
    woffT[i] = (unsigned short*)carve((size_t)9 * 80 * 64 * 2);
  unsigned short* dwP[4];
  for (int i = 0; i < 4; ++i)
    dwP[i] = (unsigned short*)carve((size_t)4 * 5 * 16 * 32 * 2);
  float* obP[4];
  for (int i = 0; i < 4; ++i) obP[i] = (float*)carve((size_t)80 * 4);

  PrepPtrs pp;
  pp.cw[0] = cr_w;
  pp.cd[0] = wcrT;
  for (int i = 0; i < 4; ++i) {
    pp.cw[i + 1] = offw[i];
    pp.cd[i + 1] = woffT[i];
    pp.dw[i] = dw[i];
    pp.dd[i] = dwP[i];
    pp.ob[i] = offb[i];
    pp.obd[i] = obP[i];
  }
  prep_all_kernel<<<dim3(288, 10), 256, 0, stream>>>(pp);

  to_gs_kernel<<<BB * NPIX / 256, 256, 0, stream>>>(Fref, Fmov1, Fmov2, frefG,
                                                    fmovG);

  const dim3 cgrid(64, BB), cblk(512);
  const dim3 fgrid(128, BB), fblk(256);
  float* outF = (float*)d_out;  // [b2][64][H][W], b2 0-3 = branch1, 4-7 = br2

  // fea = conv([Fref|Fmov], cr)                    -> feaA (GS)
  convmfma_kernel<128, 64, 64><<<cgrid, cblk, 0, stream>>>(
      frefG, 3, fmovG, 7, wcrT, cr_b, feaA);
  // fused: off1 = conv(feaA); fea = deform(feaA)   -> feaB
  fused_od_kernel<false><<<fgrid, fblk, 0, stream>>>(
      feaA, feaA, woffT[0], obP[0], dwP[0], db[0], nullptr, feaB);
  // fused: off2 = conv(feaB); fea = deform(feaB)   -> feaA
  fused_od_kernel<false><<<fgrid, fblk, 0, stream>>>(
      feaB, feaB, woffT[1], obP[1], dwP[1], db[1], nullptr, feaA);
  // fused: off3 = conv(feaA); fea = deform(fmovG)  -> feaB
  fused_od_kernel<false><<<fgrid, fblk, 0, stream>>>(
      feaA, fmovG, woffT[2], obP[2], dwP[2], db[2], nullptr, feaB);
  // fused: off4 = conv(feaB); out = deform(feaB)   -> d_out (f32 NCHW)
  fused_od_kernel<true><<<fgrid, fblk, 0, stream>>>(
      feaB, feaB, woffT[3], obP[3], dwP[3], db[3], outF, nullptr);
}

// Round 19
// 224.731 us; speedup vs baseline: 1.9564x; 1.0190x over previous
//
#include <hip/hip_runtime.h>

// AlignmentNet round 19: r18 + register-software-pipelined deform gathers
// (2-slot prefetch: tap t+1's 4 corner loads issue before tap t's interp).
// Everything else identical to round 18 (XCD swizzle, fused off-conv+deform,
// f16 packed interp, GS layouts).

using f16   = _Float16;
using f16x8 = __attribute__((ext_vector_type(8))) f16;
using h2    = __attribute__((ext_vector_type(2))) f16;
using u16x8 = __attribute__((ext_vector_type(8))) unsigned short;
using f32x4 = __attribute__((ext_vector_type(4))) float;

static constexpr int Hh = 128, Ww = 128, NB = 4, NPIX = Hh * Ww;
static constexpr int BB = 8;  // batch*branches

__device__ __forceinline__ unsigned short f2h(float f) {
  f16 h = (f16)f;
  return *(unsigned short*)&h;
}

// ---------------------------------------------------------------------------
// Fused weight prep. which: 0=cr, 1-4=off convs (cout padded 18->20 per g),
// 5-8=deform w, 9=off biases (padded to [80] in g*20+c layout).
// ---------------------------------------------------------------------------
struct PrepPtrs {
  const float* cw[5];
  unsigned short* cd[5];
  const float* dw[4];
  unsigned short* dd[4];
  const float* ob[4];
  float* obd[4];
};

__global__ __launch_bounds__(256) void prep_all_kernel(PrepPtrs pp) {
  const int which = blockIdx.y;
  const int i = blockIdx.x * 256 + threadIdx.x;
  if (which == 0) {
    if (i >= 9 * 64 * 128) return;
    const int cin = 128, cop = 64;
    const int ci = i % cin, co = (i / cin) % cop, t = i / (cin * cop);
    pp.cd[0][i] = f2h(pp.cw[0][((size_t)co * cin + ci) * 9 + t]);
  } else if (which <= 4) {
    if (i >= 9 * 80 * 64) return;
    const int cin = 64, cop = 80;
    const int ci = i % cin, co = (i / cin) % cop, t = i / (cin * cop);
    const int g = co / 20, c = co % 20;  // padded slot -> real cout g*18+c
    float v = (c < 18) ? pp.cw[which][((size_t)(g * 18 + c) * cin + ci) * 9 + t]
                       : 0.f;
    pp.cd[which][i] = f2h(v);
  } else if (which <= 8) {
    if (i >= 4 * 5 * 16 * 32) return;
    const int kk = i & 31, o = (i >> 5) & 15, pair = (i >> 9) % 5;
    const int g = i / 2560;
    const int t = pair * 2 + (kk >> 4), c = kk & 15;
    float v = (t < 9) ? pp.dw[which - 5][(size_t)((g * 16 + o) * 16 + c) * 9 + t]
                      : 0.f;
    pp.dd[which - 5][i] = f2h(v);
  } else {
    if (i >= 4 * 80) return;
    const int ten = i / 80, co = i % 80;
    const int g = co / 20, c = co % 20;
    pp.obd[ten][co] = (c < 18) ? pp.ob[ten][g * 18 + c] : 0.f;
  }
}

// ---------------------------------------------------------------------------
// NCHW f32 -> group-split f16: frefG [4][4][pix][16], fmovG [8][4][pix][16]
// ---------------------------------------------------------------------------
__global__ __launch_bounds__(256) void to_gs_kernel(
    const float* __restrict__ Fref, const float* __restrict__ Fm1,
    const float* __restrict__ Fm2, unsigned short* __restrict__ frefG,
    unsigned short* __restrict__ fmovG) {
  const int t = blockIdx.x * 256 + threadIdx.x;  // over BB*NPIX
  const int b2 = t >> 14, pix = t & (NPIX - 1);
  const float* fm = (b2 < 4 ? Fm1 : Fm2) + (size_t)(b2 & 3) * 64 * NPIX + pix;
  for (int c8 = 0; c8 < 8; ++c8) {
    u16x8 v;
#pragma unroll
    for (int j = 0; j < 8; ++j) v[j] = f2h(fm[(size_t)(c8 * 8 + j) * NPIX]);
    *(u16x8*)(fmovG + ((size_t)(b2 * 4 + (c8 >> 1)) * NPIX + pix) * 16 +
              (c8 & 1) * 8) = v;
  }
  if (b2 < 4) {
    const float* fr = Fref + (size_t)b2 * 64 * NPIX + pix;
    for (int c8 = 0; c8 < 8; ++c8) {
      u16x8 v;
#pragma unroll
      for (int j = 0; j < 8; ++j) v[j] = f2h(fr[(size_t)(c8 * 8 + j) * NPIX]);
      *(u16x8*)(frefG + ((size_t)(b2 * 4 + (c8 >> 1)) * NPIX + pix) * 16 +
                (c8 & 1) * 8) = v;
    }
  }
}

// ---------------------------------------------------------------------------
// MFMA conv 3x3 pad 1 (group-split inputs), f16. Per-tap weight ring.
// Used only for the cr conv (CIN=128 -> 64 couts, GS out). XCD-swizzled.
// ---------------------------------------------------------------------------
template <int CIN, int COP, int CO_REAL>
__global__ __launch_bounds__(512, 2) void convmfma_kernel(
    const unsigned short* __restrict__ in0, int bmask0,
    const unsigned short* __restrict__ in1, int bmask1,
    const unsigned short* __restrict__ wT,   // [9][COP][CIN] f16
    const float* __restrict__ biasP,         // [COP]
    unsigned short* __restrict__ out) {      // GS [b][g][pix][16]
  constexpr int COF = COP / 16;
  constexpr int NCH = CIN / 64;
  constexpr int NT = NCH * 9;
  __shared__ unsigned short sW[2][COP * 64];
  __shared__ unsigned short sB[324 * 64];

  const int tile = ((blockIdx.x & 7) << 3) | (blockIdx.x >> 3);  // XCD swizzle
  const int b = blockIdx.y;
  const int ty0 = (tile >> 3) << 4, tx0 = (tile & 7) << 4;
  const int tid = threadIdx.x;
  const int wv = tid >> 6, l = tid & 63;
  const int lm = l & 15, lq = l >> 4;

  f32x4 acc[COF][2];
#pragma unroll
  for (int cf = 0; cf < COF; ++cf)
#pragma unroll
    for (int pf = 0; pf < 2; ++pf) acc[cf][pf] = (f32x4){0.f, 0.f, 0.f, 0.f};

  const unsigned short* base0 = in0 + (size_t)(b & bmask0) * 4 * NPIX * 16;
  const unsigned short* base1 =
      (NCH > 1) ? in1 + (size_t)(b & bmask1) * 4 * NPIX * 16 : nullptr;

  auto stage_input = [&](int ch) {
    const unsigned short* inB = (ch == 0) ? base0 : base1;
    for (int q = tid; q < 324 * 8; q += 512) {
      const int pix = q >> 3, ci8 = q & 7;
      const int r = pix / 18, c = pix - r * 18;
      const int gy = ty0 - 1 + r, gx = tx0 - 1 + c;
      u16x8 v;
      if (gy >= 0 && gy < Hh && gx >= 0 && gx < Ww) {
        v = *(const u16x8*)(inB + ((size_t)(ci8 >> 1) * NPIX + gy * Ww + gx) *
                                      16 + (ci8 & 1) * 8);
      } else {
#pragma unroll
        for (int j = 0; j < 8; ++j) v[j] = 0;
      }
      const int boff = pix * 128 + ((ci8 * 16) ^ ((pix & 7) << 4));
      *(u16x8*)((char*)sB + boff) = v;
    }
  };
  auto stage_w = [&](int tt, int buf) {
    const int ch = tt / 9, t = tt - ch * 9;
    for (int q = tid; q < COP * 8; q += 512) {
      const int ci8 = q & 7;
      const int co = q >> 3;
      u16x8 v = *(const u16x8*)(wT + (size_t)(t * COP + co) * CIN + ch * 64 +
                                ci8 * 8);
      const int aoff = co * 128 + ((ci8 * 16) ^ ((co & 7) << 4));
      *(u16x8*)((char*)sW[buf] + aoff) = v;
    }
  };

  stage_input(0);
  stage_w(0, 0);
  __syncthreads();

  for (int tt = 0; tt < NT; ++tt) {
    const int t = tt % 9;
    const bool nextNewCh = ((tt + 1) % 9 == 0);
    if (tt + 1 < NT && !nextNewCh) stage_w(tt + 1, (tt + 1) & 1);

    const int dy = t / 3, dx = t - dy * 3;
    const char* sWc = (const char*)sW[tt & 1];
#pragma unroll
    for (int kc = 0; kc < 2; ++kc) {
      f16x8 afr[COF];
#pragma unroll
      for (int cf = 0; cf < COF; ++cf) {
        const int co = cf * 16 + lm;
        const int aoff = co * 128 + ((kc * 64 + lq * 16) ^ ((co & 7) << 4));
        afr[cf] = *(const f16x8*)(sWc + aoff);
      }
#pragma unroll
      for (int pf = 0; pf < 2; ++pf) {
        const int pix = wv * 32 + pf * 16 + lm;
        const int spix = ((pix >> 4) + dy) * 18 + (pix & 15) + dx;
        const int boff = spix * 128 + ((kc * 64 + lq * 16) ^ ((spix & 7) << 4));
        const f16x8 bfr = *(const f16x8*)((const char*)sB + boff);
#pragma unroll
        for (int cf = 0; cf < COF; ++cf)
          acc[cf][pf] = __builtin_amdgcn_mfma_f32_16x16x32_f16(
              afr[cf], bfr, acc[cf][pf], 0, 0, 0);
      }
    }
    __syncthreads();
    if (tt + 1 < NT && nextNewCh) {
      stage_input((tt + 1) / 9);
      stage_w(tt + 1, (tt + 1) & 1);
      __syncthreads();
    }
  }

#pragma unroll
  for (int cf = 0; cf < COF; ++cf) {
    const int co0 = cf * 16 + lq * 4;
    if (co0 >= CO_REAL) continue;
    const float4 bv = *(const float4*)(biasP + co0);
#pragma unroll
    for (int pf = 0; pf < 2; ++pf) {
      const int pix = wv * 32 + pf * 16 + lm;
      const int gpix = (ty0 + (pix >> 4)) * Ww + tx0 + (pix & 15);
      const f32x4 v = acc[cf][pf];
      ushort4 pk;
      pk.x = f2h(v[0] + bv.x);
      pk.y = f2h(v[1] + bv.y);
      pk.z = f2h(v[2] + bv.z);
      pk.w = f2h(v[3] + bv.w);
      const int gg = co0 >> 4, cc = co0 & 15;
      *(ushort4*)(out + ((size_t)(b * 4 + gg) * NPIX + gpix) * 16 + cc) = pk;
    }
  }
}

// ---------------------------------------------------------------------------
// FUSED off-conv + deform, 4x32 tile, 256 thr (4 waves). Phase 1 as r18.
// Phase 2: deform with 2-slot REGISTER prefetch pipeline on the bilinear
// gathers (tap t+1's loads issue before tap t's interp). XCD-swizzled.
// ---------------------------------------------------------------------------
template <bool NCHW_OUT>
__global__ __launch_bounds__(256, 3) void fused_od_kernel(
    const unsigned short* __restrict__ convIn,  // [b][4][pix][16] f16
    const unsigned short* __restrict__ sampX,   // [b][4][pix][16] f16
    const unsigned short* __restrict__ wT,      // [9][80][64] f16
    const float* __restrict__ obias,            // [80] padded
    const unsigned short* __restrict__ dwP,     // [4][5][16][32] f16
    const float* __restrict__ dbias,            // [64]
    float* __restrict__ outF, unsigned short* __restrict__ outH) {
  __shared__ __attribute__((aligned(16))) char lds[36352];
  char* sB = lds;               // halo: 204 px * 128B
  char* sW = lds + 26112;       // 80 co * 128B
  char* sOffB = lds;            // [128][168B]
  char* bounce = lds + 26112;   // [128][80B]

  const int tile = ((blockIdx.x & 7) << 4) | (blockIdx.x >> 3);  // XCD swizzle
  const int b = blockIdx.y;
  const int ty0 = (tile >> 2) << 2;   // 32 tile-rows of 4
  const int tx0 = (tile & 3) << 5;    // 4 tile-cols of 32
  const int tid = threadIdx.x;
  const int wv = tid >> 6, l = tid & 63;
  const int lm = l & 15, lq = l >> 4;

  // ================= phase 1: offset conv (CIN=64, COP=80) =================
  f32x4 acc[5][2];
#pragma unroll
  for (int cf = 0; cf < 5; ++cf)
#pragma unroll
    for (int pf = 0; pf < 2; ++pf) acc[cf][pf] = (f32x4){0.f, 0.f, 0.f, 0.f};

  const unsigned short* inB = convIn + (size_t)b * 4 * NPIX * 16;

  u16x8 wr0, wr1, wr2;
  auto wload = [&](int t) {
    const unsigned short* wt = wT + (size_t)t * 5120;
    wr0 = *(const u16x8*)(wt + (size_t)(tid >> 3) * 64 + (tid & 7) * 8);
    const int q1 = tid + 256;
    wr1 = *(const u16x8*)(wt + (size_t)(q1 >> 3) * 64 + (q1 & 7) * 8);
    if (tid < 128) {
      const int q2 = tid + 512;
      wr2 = *(const u16x8*)(wt + (size_t)(q2 >> 3) * 64 + (q2 & 7) * 8);
    }
  };
  auto wstore = [&]() {
    auto put = [&](int q, u16x8 v) {
      const int co = q >> 3, ci8 = q & 7;
      *(u16x8*)(sW + co * 128 + ((ci8 * 16) ^ ((co & 7) << 4))) = v;
    };
    put(tid, wr0);
    put(tid + 256, wr1);
    if (tid < 128) put(tid + 512, wr2);
  };

  wload(0);
  for (int q = tid; q < 204 * 8; q += 256) {
    const int pix = q >> 3, ci8 = q & 7;
    const int r = pix / 34, c = pix - r * 34;
    const int gy = ty0 - 1 + r, gx = tx0 - 1 + c;
    u16x8 v;
    if (gy >= 0 && gy < Hh && gx >= 0 && gx < Ww) {
      v = *(const u16x8*)(inB + ((size_t)(ci8 >> 1) * NPIX + gy * Ww + gx) *
                                    16 + (ci8 & 1) * 8);
    } else {
#pragma unroll
      for (int j = 0; j < 8; ++j) v[j] = 0;
    }
    const int boff = pix * 128 + ((ci8 * 16) ^ ((pix & 7) << 4));
    *(u16x8*)(sB + boff) = v;
  }
  wstore();
  __syncthreads();

  for (int t = 0; t < 9; ++t) {
    if (t + 1 < 9) wload(t + 1);
    const int dy = t / 3, dx = t - dy * 3;
#pragma unroll
    for (int kc = 0; kc < 2; ++kc) {
      f16x8 afr[5];
#pragma unroll
      for (int cf = 0; cf < 5; ++cf) {
        const int co = cf * 16 + lm;
        const int aoff = co * 128 + ((kc * 64 + lq * 16) ^ ((co & 7) << 4));
        afr[cf] = *(const f16x8*)(sW + aoff);
      }
#pragma unroll
      for (int pf = 0; pf < 2; ++pf) {
        const int pix = wv * 32 + pf * 16 + lm;
        const int spix = ((pix >> 5) + dy) * 34 + (pix & 31) + dx;
        const int boff = spix * 128 + ((kc * 64 + lq * 16) ^ ((spix & 7) << 4));
        const f16x8 bfr = *(const f16x8*)(sB + boff);
#pragma unroll
        for (int cf = 0; cf < 5; ++cf)
          acc[cf][pf] = __builtin_amdgcn_mfma_f32_16x16x32_f16(
              afr[cf], bfr, acc[cf][pf], 0, 0, 0);
      }
    }
    __syncthreads();
    if (t + 1 < 9) {
      wstore();
      __syncthreads();
    }
  }

  // epilogue -> sOff [128][168B]
#pragma unroll
  for (int cf = 0; cf < 5; ++cf) {
    const int co0 = cf * 16 + lq * 4;
    const float4 bv = *(const float4*)(obias + co0);
#pragma unroll
    for (int pf = 0; pf < 2; ++pf) {
      const int pix = wv * 32 + pf * 16 + lm;
      const f32x4 v = acc[cf][pf];
      ushort4 pk;
      pk.x = f2h(v[0] + bv.x);
      pk.y = f2h(v[1] + bv.y);
      pk.z = f2h(v[2] + bv.z);
      pk.w = f2h(v[3] + bv.w);
      *(ushort4*)(sOffB + pix * 168 + co0 * 2) = pk;
    }
  }
  __syncthreads();

  // ================= phase 2: deform with 2-slot gather pipeline ===========
  const int p = tid >> 1, h = tid & 1;  // pixel 0..127, channel-half
  const int y = ty0 + (p >> 5), xx = tx0 + (p & 31);
  char* myB = bounce + p * 80 + h * 16;

  for (int g = 0; g < 4; ++g) {
    const unsigned short* xP =
        sampX + (size_t)(b * 4 + g) * NPIX * 16 + h * 8;

    f16x8 afr[5];
#pragma unroll
    for (int pr = 0; pr < 5; ++pr)
      afr[pr] = *(const f16x8*)(dwP + ((size_t)(g * 5 + pr) * 16 + lm) * 32 +
                                lq * 8);

    f32x4 dacc[2];
    dacc[0] = (f32x4){0.f, 0.f, 0.f, 0.f};
    dacc[1] = (f32x4){0.f, 0.f, 0.f, 0.f};

    // 2-slot register pipeline for gathers
    u16x8 ld[2][4];
    f16 wgt[2][4];

    auto prefetch = [&](int t, int slot) {
      float dyo = 0.f, dxo = 0.f;
      if (t < 9) {
        const unsigned odw =
            *(const unsigned*)(sOffB + p * 168 + (g * 20 + 2 * t) * 2);
        const f16* op = (const f16*)&odw;
        dyo = (float)op[0];
        dxo = (float)op[1];
      }
      const int tc = (t < 9) ? t : 0;
      const float act = (t < 9) ? 1.f : 0.f;
      const float py = dyo + (float)(y - 2 + 2 * (tc / 3));
      const float px = dxo + (float)(xx - 2 + 2 * (tc % 3));
      const float fy = floorf(py), fx = floorf(px);
      const int y0 = (int)fy, x0 = (int)fx;
      const int y1 = y0 + 1, x1 = x0 + 1;
      const float ly = py - fy, lx = px - fx;
      float w00 = (1.f - ly) * (1.f - lx) * act, w01 = (1.f - ly) * lx * act;
      float w10 = ly * (1.f - lx) * act, w11 = ly * lx * act;
      const bool vy0 = (y0 >= 0) && (y0 < Hh), vy1 = (y1 >= 0) && (y1 < Hh);
      const bool vx0 = (x0 >= 0) && (x0 < Ww), vx1 = (x1 >= 0) && (x1 < Ww);
      w00 = (vy0 && vx0) ? w00 : 0.f;
      w01 = (vy0 && vx1) ? w01 : 0.f;
      w10 = (vy1 && vx0) ? w10 : 0.f;
      w11 = (vy1 && vx1) ? w11 : 0.f;
      const int y0c = min(max(y0, 0), Hh - 1), y1c = min(max(y1, 0), Hh - 1);
      const int x0c = min(max(x0, 0), Ww - 1), x1c = min(max(x1, 0), Ww - 1);
      ld[slot][0] = *(const u16x8*)(xP + (size_t)(y0c * Ww + x0c) * 16);
      ld[slot][1] = *(const u16x8*)(xP + (size_t)(y0c * Ww + x1c) * 16);
      ld[slot][2] = *(const u16x8*)(xP + (size_t)(y1c * Ww + x0c) * 16);
      ld[slot][3] = *(const u16x8*)(xP + (size_t)(y1c * Ww + x1c) * 16);
      wgt[slot][0] = (f16)w00;
      wgt[slot][1] = (f16)w01;
      wgt[slot][2] = (f16)w10;
      wgt[slot][3] = (f16)w11;
    };
    auto consume = [&](int slot, char* dst) {
      const h2* c00 = (const h2*)&ld[slot][0];
      const h2* c01 = (const h2*)&ld[slot][1];
      const h2* c10 = (const h2*)&ld[slot][2];
      const h2* c11 = (const h2*)&ld[slot][3];
      const h2 p00 = (h2){wgt[slot][0], wgt[slot][0]};
      const h2 p01 = (h2){wgt[slot][1], wgt[slot][1]};
      const h2 p10 = (h2){wgt[slot][2], wgt[slot][2]};
      const h2 p11 = (h2){wgt[slot][3], wgt[slot][3]};
      unsigned fw[4];
#pragma unroll
      for (int j = 0; j < 4; ++j) {
        h2 r = c00[j] * p00;
        r += c01[j] * p01;
        r += c10[j] * p10;
        r += c11[j] * p11;
        fw[j] = *(const unsigned*)&r;
      }
      *(uint4*)dst = (uint4){fw[0], fw[1], fw[2], fw[3]};
    };

    prefetch(0, 0);
#pragma unroll
    for (int pair = 0; pair < 5; ++pair) {
      prefetch(pair * 2 + 1, 1);        // next tap's loads in flight
      consume(0, myB);                  // interp tap 2*pair (slot 0)
      if (pair < 4) prefetch(pair * 2 + 2, 0);
      consume(1, myB + 32);             // interp tap 2*pair+1 (slot 1)
#pragma unroll
      for (int n = 0; n < 2; ++n) {
        const f16x8 bfr =
            *(const f16x8*)(bounce + (wv * 32 + n * 16 + lm) * 80 + lq * 16);
        dacc[n] = __builtin_amdgcn_mfma_f32_16x16x32_f16(afr[pair], bfr,
                                                         dacc[n], 0, 0, 0);
      }
    }

    const float4 bv = *(const float4*)(dbias + g * 16 + lq * 4);
#pragma unroll
    for (int n = 0; n < 2; ++n) {
      const int pixl = wv * 32 + n * 16 + lm;
      const int gpix = (ty0 + (pixl >> 5)) * Ww + tx0 + (pixl & 31);
      const f32x4 v = dacc[n];
      if (NCHW_OUT) {
        float* oB = outF + (size_t)(b * 64 + g * 16 + lq * 4) * NPIX + gpix;
        oB[0] = v[0] + bv.x;
        oB[NPIX] = v[1] + bv.y;
        oB[2 * NPIX] = v[2] + bv.z;
        oB[3 * NPIX] = v[3] + bv.w;
      } else {
        ushort4 pk;
        pk.x = f2h(v[0] + bv.x);
        pk.y = f2h(v[1] + bv.y);
        pk.z = f2h(v[2] + bv.z);
        pk.w = f2h(v[3] + bv.w);
        *(ushort4*)(outH + ((size_t)(b * 4 + g) * NPIX + gpix) * 16 + lq * 4) =
            pk;
      }
    }
  }
}

// ---------------------------------------------------------------------------

extern "C" void kernel_launch(void* const* d_in, const int* in_sizes, int n_in,
                              void* d_out, int out_size, void* d_ws,
                              size_t ws_size, hipStream_t stream) {
  const float* Fref = (const float*)d_in[0];
  const float* Fmov1 = (const float*)d_in[1];
  const float* Fmov2 = (const float*)d_in[2];
  const float* cr_w = (const float*)d_in[3];
  const float* cr_b = (const float*)d_in[4];
  const float* offw[4] = {(const float*)d_in[5], (const float*)d_in[7],
                          (const float*)d_in[9], (const float*)d_in[11]};
  const float* offb[4] = {(const float*)d_in[6], (const float*)d_in[8],
                          (const float*)d_in[10], (const float*)d_in[12]};
  const float* dw[4] = {(const float*)d_in[13], (const float*)d_in[15],
                        (const float*)d_in[17], (const float*)d_in[19]};
  const float* db[4] = {(const float*)d_in[14], (const float*)d_in[16],
                        (const float*)d_in[18], (const float*)d_in[20]};

  char* p = (char*)d_ws;
  auto carve = [&](size_t bytes) {
    void* r = p;
    p += (bytes + 255) & ~(size_t)255;
    return r;
  };
  unsigned short* frefG = (unsigned short*)carve((size_t)4 * 4 * NPIX * 16 * 2);
  unsigned short* fmovG = (unsigned short*)carve((size_t)BB * 4 * NPIX * 16 * 2);
  unsigned short* feaA = (unsigned short*)carve((size_t)BB * 4 * NPIX * 16 * 2);
  unsigned short* feaB = (unsigned short*)carve((size_t)BB * 4 * NPIX * 16 * 2);
  unsigned short* wcrT = (unsigned short*)carve((size_t)9 * 64 * 128 * 2);
  unsigned short* woffT[4];
  for (int i = 0; i < 4; ++i)
    woffT[i] = (unsigned short*)carve((size_t)9 * 80 * 64 * 2);
  unsigned short* dwP[4];
  for (int i = 0; i < 4; ++i)
    dwP[i] = (unsigned short*)carve((size_t)4 * 5 * 16 * 32 * 2);
  float* obP[4];
  for (int i = 0; i < 4; ++i) obP[i] = (float*)carve((size_t)80 * 4);

  PrepPtrs pp;
  pp.cw[0] = cr_w;
  pp.cd[0] = wcrT;
  for (int i = 0; i < 4; ++i) {
    pp.cw[i + 1] = offw[i];
    pp.cd[i + 1] = woffT[i];
    pp.dw[i] = dw[i];
    pp.dd[i] = dwP[i];
    pp.ob[i] = offb[i];
    pp.obd[i] = obP[i];
  }
  prep_all_kernel<<<dim3(288, 10), 256, 0, stream>>>(pp);

  to_gs_kernel<<<BB * NPIX / 256, 256, 0, stream>>>(Fref, Fmov1, Fmov2, frefG,
                                                    fmovG);

  const dim3 cgrid(64, BB), cblk(512);
  const dim3 fgrid(128, BB), fblk(256);
  float* outF = (float*)d_out;  // [b2][64][H][W], b2 0-3 = branch1, 4-7 = br2

  // fea = conv([Fref|Fmov], cr)                    -> feaA (GS)
  convmfma_kernel<128, 64, 64><<<cgrid, cblk, 0, stream>>>(
      frefG, 3, fmovG, 7, wcrT, cr_b, feaA);
  // fused: off1 = conv(feaA); fea = deform(feaA)   -> feaB
  fused_od_kernel<false><<<fgrid, fblk, 0, stream>>>(
      feaA, feaA, woffT[0], obP[0], dwP[0], db[0], nullptr, feaB);
  // fused: off2 = conv(feaB); fea = deform(feaB)   -> feaA
  fused_od_kernel<false><<<fgrid, fblk, 0, stream>>>(
      feaB, feaB, woffT[1], obP[1], dwP[1], db[1], nullptr, feaA);
  // fused: off3 = conv(feaA); fea = deform(fmovG)  -> feaB
  fused_od_kernel<false><<<fgrid, fblk, 0, stream>>>(
      feaA, fmovG, woffT[2], obP[2], dwP[2], db[2], nullptr, feaB);
  // fused: off4 = conv(feaB); out = deform(feaB)   -> d_out (f32 NCHW)
  fused_od_kernel<true><<<fgrid, fblk, 0, stream>>>(
      feaB, feaB, woffT[3], obP[3], dwP[3], db[3], outF, nullptr);
}